// Round 9
// baseline (1511.705 us; speedup 1.0000x reference)
//
#include <hip/hip_runtime.h>

typedef float f4 __attribute__((ext_vector_type(4)));

#define NPIX (32*512*512)        // 8388608
#define BN_EPS 1e-5f
#define GRID_MAIN 2048
#define NIT_MAIN  4              // 2048 blocks * 4 tiles * 1024 px = NPIX
#define GRID_MOM  1024
#define NIT_MOM   8              // 1024 blocks * 8 tiles * 1024 px = NPIX

// ws float layout:
// [0..5]   M1 sums of s_i
// [6..26]  M2 sums (upper tri, idx = 6 + a*(11-a)/2 + b, a<=b)
// [27]     S1 (sum o_pre), [28] S2 (sum o_pre^2)
// [29]     a2, [30] c2
// [32..232)  wpack[25][8] = {a1w0..a1w5, beff, w2c}
// [400..]  zbuf (zero region)
// memset clears first 2048 bytes each launch.

struct Rows { f4 C, N, S; float wv, ev, nwv, sev; };

__device__ __forceinline__ Rows loadrows(const float* __restrict__ x,
                                         const float* zbuf, int p) {
    Rows r;
    int rem = p & (512*512 - 1);
    int i = rem >> 9, jj = rem & 511;          // jj multiple of 4
    const float* xc = x + p;
    const float* xn = (i > 0)   ? xc - 512 : zbuf;
    const float* xs = (i < 511) ? xc + 512 : zbuf;
    r.C = *(const f4*)xc;
    r.N = *(const f4*)xn;
    r.S = *(const f4*)xs;
    bool hw = (jj > 0), he = (jj < 508);
    float wv  = xc[hw ? -1 : 0];
    float ev  = xc[he ?  4 : 3];
    float nwv = xn[hw ? -1 : 0];
    float sev = xs[he ?  4 : 3];
    r.wv  = hw ? wv  : 0.f;
    r.ev  = he ? ev  : 0.f;
    r.nwv = hw ? nwv : 0.f;
    r.sev = he ? sev : 0.f;
    return r;
}

__device__ __forceinline__ void mkstencil(const Rows& r, f4 s[6]) {
    f4 E   = {r.C.y, r.C.z, r.C.w, r.ev};
    f4 W   = {r.wv,  r.C.x, r.C.y, r.C.z};
    f4 Ssh = {r.S.y, r.S.z, r.S.w, r.sev};
    f4 Nsh = {r.nwv, r.N.x, r.N.y, r.N.z};
    s[0] = r.C;
    s[1] = (r.S - r.N) * 0.5f;
    s[2] = (E - W) * 0.5f;
    s[3] = r.S + r.N - 2.f*r.C;
    s[4] = E + W - 2.f*r.C;
    s[5] = Ssh + Nsh - r.S - E;
}

__device__ __forceinline__ f4 vmax0(f4 a) {
    f4 r;
    r.x = fmaxf(a.x, 0.f); r.y = fmaxf(a.y, 0.f);
    r.z = fmaxf(a.z, 0.f); r.w = fmaxf(a.w, 0.f);
    return r;
}

// ---------------- k_moments: grid-stride + prefetch ----------------
__global__ __launch_bounds__(256) void k_moments(const float* __restrict__ x,
                                                 float* ws) {
    const float* zbuf = ws + 400;
    int t = threadIdx.x;
    float acc[27];
    #pragma unroll
    for (int i = 0; i < 27; ++i) acc[i] = 0.f;

    // tile T = blockIdx.x*NIT_MOM + it ; pixel group g = T*256 + t
    int T0 = blockIdx.x * NIT_MOM;
    Rows P = loadrows(x, zbuf, (T0*256 + t) * 4);
    #pragma unroll 1
    for (int it = 0; it < NIT_MOM; ++it) {
        Rows cur = P;
        if (it + 1 < NIT_MOM)
            P = loadrows(x, zbuf, ((T0 + it + 1)*256 + t) * 4);
        f4 s[6];
        mkstencil(cur, s);
        #pragma unroll
        for (int a = 0; a < 6; ++a) {
            acc[a] += (s[a].x + s[a].y) + (s[a].z + s[a].w);
            #pragma unroll
            for (int b = a; b < 6; ++b) {
                int idx = 6 + a*(11-a)/2 + b;
                float v = acc[idx];
                v = fmaf(s[a].x, s[b].x, v);
                v = fmaf(s[a].y, s[b].y, v);
                v = fmaf(s[a].z, s[b].z, v);
                v = fmaf(s[a].w, s[b].w, v);
                acc[idx] = v;
            }
        }
    }
    #pragma unroll
    for (int i = 0; i < 27; ++i) {
        float v = acc[i];
        for (int off = 32; off; off >>= 1) v += __shfl_xor(v, off);
        acc[i] = v;
    }
    __shared__ float red[27][4];
    int wave = t >> 6, lane = t & 63;
    if (lane == 0)
        for (int i = 0; i < 27; ++i) red[i][wave] = acc[i];
    __syncthreads();
    if (t < 27) atomicAdd(&ws[t], red[t][0] + red[t][1] + red[t][2] + red[t][3]);
}

__global__ void k_stats1(const float* w1, const float* b1, const float* g1,
                         const float* beta1, const float* w2, float* ws) {
    int c = threadIdx.x;
    if (c >= 25) return;
    const float invN = 1.f / (float)NPIX;
    float m1[6], wr[6];
    #pragma unroll
    for (int i = 0; i < 6; ++i) m1[i] = ws[i] * invN;
    #pragma unroll
    for (int i = 0; i < 6; ++i) wr[i] = w1[c*6 + i];
    float bc = b1[c];
    float mean = bc;
    #pragma unroll
    for (int i = 0; i < 6; ++i) mean = fmaf(wr[i], m1[i], mean);
    float e2 = bc * bc;
    #pragma unroll
    for (int i = 0; i < 6; ++i) e2 = fmaf(2.f*bc*wr[i], m1[i], e2);
    #pragma unroll
    for (int i = 0; i < 6; ++i)
        #pragma unroll
        for (int j = 0; j < 6; ++j) {
            int a = i < j ? i : j, b = i < j ? j : i;
            float m2 = ws[6 + a*(11-a)/2 + b] * invN;
            e2 = fmaf(wr[i]*wr[j], m2, e2);
        }
    float var = e2 - mean*mean;
    float a1 = g1[c] * rsqrtf(var + BN_EPS);
    float* wp = ws + 32 + c*8;
    #pragma unroll
    for (int i = 0; i < 6; ++i) wp[i] = a1 * wr[i];
    wp[6] = fmaf(a1, bc - mean, beta1[c]);   // beff
    wp[7] = w2[c];                           // w2c
}

// ---------------- k_main: grid-stride + prefetch, plain-C conv ----------------
__global__ __launch_bounds__(256) void k_main(const float* __restrict__ x,
                                              const float* __restrict__ wts,
                                              const float* __restrict__ zbuf,
                                              const float* __restrict__ b2,
                                              float* __restrict__ stats,
                                              float* __restrict__ opre) {
    __shared__ f4 lw[50];                    // 25 channels x {w0..w3},{w4,w5,beff,w2c}
    int t = threadIdx.x;
    if (t < 50) lw[t] = ((const f4*)wts)[t];
    __syncthreads();

    float b2v = b2[0];
    float l1 = 0.f, l2 = 0.f;
    int T0 = blockIdx.x * NIT_MAIN;

    Rows P = loadrows(x, zbuf, (T0*256 + t) * 4);
    #pragma unroll 1
    for (int it = 0; it < NIT_MAIN; ++it) {
        Rows cur = P;
        if (it + 1 < NIT_MAIN)
            P = loadrows(x, zbuf, ((T0 + it + 1)*256 + t) * 4);

        f4 s[6];
        mkstencil(cur, s);

        f4 o = {b2v, b2v, b2v, b2v};
        #pragma unroll
        for (int c = 0; c < 25; ++c) {
            f4 A = lw[2*c];                  // w0 w1 w2 w3
            f4 B = lw[2*c + 1];              // w4 w5 beff w2c
            f4 tt = {B.z, B.z, B.z, B.z};
            tt += s[0] * A.x;
            tt += s[1] * A.y;
            tt += s[2] * A.z;
            tt += s[3] * A.w;
            tt += s[4] * B.x;
            tt += s[5] * B.y;
            tt = vmax0(tt);
            o += tt * B.w;
        }

        *(f4*)(opre + ((T0 + it)*256 + t) * 4) = o;
        l1 += (o.x + o.y) + (o.z + o.w);
        l2 = fmaf(o.x, o.x, l2); l2 = fmaf(o.y, o.y, l2);
        l2 = fmaf(o.z, o.z, l2); l2 = fmaf(o.w, o.w, l2);
    }

    for (int off = 32; off; off >>= 1) { l1 += __shfl_xor(l1, off); l2 += __shfl_xor(l2, off); }
    __shared__ float red[2][4];
    int wave = t >> 6, lane = t & 63;
    if (lane == 0) { red[0][wave] = l1; red[1][wave] = l2; }
    __syncthreads();
    if (t == 0) atomicAdd(&stats[27], red[0][0]+red[0][1]+red[0][2]+red[0][3]);
    if (t == 1) atomicAdd(&stats[28], red[1][0]+red[1][1]+red[1][2]+red[1][3]);
}

__global__ void k_stats2(const float* g2, const float* beta2, float* ws) {
    const float invN = 1.f / (float)NPIX;
    float mean = ws[27] * invN;
    float var  = ws[28] * invN - mean*mean;
    float a2 = g2[0] * rsqrtf(var + BN_EPS);
    ws[29] = a2;
    ws[30] = fmaf(-mean, a2, beta2[0]);
}

__global__ __launch_bounds__(256) void k_final(const float* __restrict__ x,
                                               const float* ws,
                                               float* out) {
    int idx = blockIdx.x * 256 + threadIdx.x;   // float4 index
    float a2 = ws[29], c2 = ws[30];
    f4 o  = ((const f4*)out)[idx];
    f4 xv = ((const f4*)x)[idx];
    f4 r;
    r.x = fmaxf(fmaf(a2, o.x, c2), 0.f) + xv.x;
    r.y = fmaxf(fmaf(a2, o.y, c2), 0.f) + xv.y;
    r.z = fmaxf(fmaf(a2, o.z, c2), 0.f) + xv.z;
    r.w = fmaxf(fmaf(a2, o.w, c2), 0.f) + xv.w;
    ((f4*)out)[idx] = r;
}

extern "C" void kernel_launch(void* const* d_in, const int* in_sizes, int n_in,
                              void* d_out, int out_size, void* d_ws, size_t ws_size,
                              hipStream_t stream) {
    const float* x     = (const float*)d_in[0];
    const float* w1    = (const float*)d_in[1];
    const float* b1    = (const float*)d_in[2];
    const float* g1    = (const float*)d_in[3];
    const float* beta1 = (const float*)d_in[4];
    const float* w2    = (const float*)d_in[5];
    const float* b2    = (const float*)d_in[6];
    const float* g2    = (const float*)d_in[7];
    const float* beta2 = (const float*)d_in[8];
    float* out = (float*)d_out;
    float* ws  = (float*)d_ws;

    hipMemsetAsync(ws, 0, 2048, stream);
    k_moments<<<GRID_MOM, 256, 0, stream>>>(x, ws);
    k_stats1 <<<1, 32, 0, stream>>>(w1, b1, g1, beta1, w2, ws);
    k_main   <<<GRID_MAIN, 256, 0, stream>>>(x, ws + 32, ws + 400, b2, ws, out);
    k_stats2 <<<1, 1, 0, stream>>>(g2, beta2, ws);
    k_final  <<<8192, 256, 0, stream>>>(x, ws, out);
}

// Round 10
// 1509.553 us; speedup vs baseline: 1.0014x; 1.0014x over previous
//
#include <hip/hip_runtime.h>

typedef float f4 __attribute__((ext_vector_type(4)));

#define NPIX (32*512*512)        // 8388608
#define BN_EPS 1e-5f
#define GRID_MAIN 2048
#define NIT_MAIN  4              // 2048 blocks * 4 tiles * 1024 px = NPIX
#define GRID_MOM  1024
#define NIT_MOM   8              // 1024 blocks * 8 tiles * 1024 px = NPIX

// ws float layout:
// [0..5]   M1 sums of s_i
// [6..26]  M2 sums (upper tri, idx = 6 + a*(11-a)/2 + b, a<=b)
// [27]     S1 (sum o_pre), [28] S2 (sum o_pre^2)
// [29]     a2, [30] c2
// [32..232)  wpack[25][8] = {a1w0..a1w5, beff, w2c}
// [400..]  zbuf (zero region)
// memset clears first 2048 bytes each launch.

struct Rows { f4 C, N, S; float wv, ev, nwv, sev; };

__device__ __forceinline__ Rows loadrows(const float* __restrict__ x,
                                         const float* zbuf, int p) {
    Rows r;
    int rem = p & (512*512 - 1);
    int i = rem >> 9, jj = rem & 511;          // jj multiple of 4
    const float* xc = x + p;
    const float* xn = (i > 0)   ? xc - 512 : zbuf;
    const float* xs = (i < 511) ? xc + 512 : zbuf;
    r.C = *(const f4*)xc;
    r.N = *(const f4*)xn;
    r.S = *(const f4*)xs;
    bool hw = (jj > 0), he = (jj < 508);
    float wv  = xc[hw ? -1 : 0];
    float ev  = xc[he ?  4 : 3];
    float nwv = xn[hw ? -1 : 0];
    float sev = xs[he ?  4 : 3];
    r.wv  = hw ? wv  : 0.f;
    r.ev  = he ? ev  : 0.f;
    r.nwv = hw ? nwv : 0.f;
    r.sev = he ? sev : 0.f;
    return r;
}

__device__ __forceinline__ void mkstencil(const Rows& r, f4 s[6]) {
    f4 E   = {r.C.y, r.C.z, r.C.w, r.ev};
    f4 W   = {r.wv,  r.C.x, r.C.y, r.C.z};
    f4 Ssh = {r.S.y, r.S.z, r.S.w, r.sev};
    f4 Nsh = {r.nwv, r.N.x, r.N.y, r.N.z};
    s[0] = r.C;
    s[1] = (r.S - r.N) * 0.5f;
    s[2] = (E - W) * 0.5f;
    s[3] = r.S + r.N - 2.f*r.C;
    s[4] = E + W - 2.f*r.C;
    s[5] = Ssh + Nsh - r.S - E;
}

__device__ __forceinline__ f4 vmax0(f4 a) {
    f4 r;
    r.x = fmaxf(a.x, 0.f); r.y = fmaxf(a.y, 0.f);
    r.z = fmaxf(a.z, 0.f); r.w = fmaxf(a.w, 0.f);
    return r;
}

// ---------------- k_moments: grid-stride + prefetch ----------------
__global__ __launch_bounds__(256) void k_moments(const float* __restrict__ x,
                                                 float* ws) {
    const float* zbuf = ws + 400;
    int t = threadIdx.x;
    float acc[27];
    #pragma unroll
    for (int i = 0; i < 27; ++i) acc[i] = 0.f;

    // tile T = blockIdx.x*NIT_MOM + it ; pixel group g = T*256 + t
    int T0 = blockIdx.x * NIT_MOM;
    Rows P = loadrows(x, zbuf, (T0*256 + t) * 4);
    #pragma unroll 1
    for (int it = 0; it < NIT_MOM; ++it) {
        Rows cur = P;
        if (it + 1 < NIT_MOM)
            P = loadrows(x, zbuf, ((T0 + it + 1)*256 + t) * 4);
        f4 s[6];
        mkstencil(cur, s);
        #pragma unroll
        for (int a = 0; a < 6; ++a) {
            acc[a] += (s[a].x + s[a].y) + (s[a].z + s[a].w);
            #pragma unroll
            for (int b = a; b < 6; ++b) {
                int idx = 6 + a*(11-a)/2 + b;
                float v = acc[idx];
                v = fmaf(s[a].x, s[b].x, v);
                v = fmaf(s[a].y, s[b].y, v);
                v = fmaf(s[a].z, s[b].z, v);
                v = fmaf(s[a].w, s[b].w, v);
                acc[idx] = v;
            }
        }
    }
    #pragma unroll
    for (int i = 0; i < 27; ++i) {
        float v = acc[i];
        for (int off = 32; off; off >>= 1) v += __shfl_xor(v, off);
        acc[i] = v;
    }
    __shared__ float red[27][4];
    int wave = t >> 6, lane = t & 63;
    if (lane == 0)
        for (int i = 0; i < 27; ++i) red[i][wave] = acc[i];
    __syncthreads();
    if (t < 27) atomicAdd(&ws[t], red[t][0] + red[t][1] + red[t][2] + red[t][3]);
}

__global__ void k_stats1(const float* w1, const float* b1, const float* g1,
                         const float* beta1, const float* w2, float* ws) {
    int c = threadIdx.x;
    if (c >= 25) return;
    const float invN = 1.f / (float)NPIX;
    float m1[6], wr[6];
    #pragma unroll
    for (int i = 0; i < 6; ++i) m1[i] = ws[i] * invN;
    #pragma unroll
    for (int i = 0; i < 6; ++i) wr[i] = w1[c*6 + i];
    float bc = b1[c];
    float mean = bc;
    #pragma unroll
    for (int i = 0; i < 6; ++i) mean = fmaf(wr[i], m1[i], mean);
    float e2 = bc * bc;
    #pragma unroll
    for (int i = 0; i < 6; ++i) e2 = fmaf(2.f*bc*wr[i], m1[i], e2);
    #pragma unroll
    for (int i = 0; i < 6; ++i)
        #pragma unroll
        for (int j = 0; j < 6; ++j) {
            int a = i < j ? i : j, b = i < j ? j : i;
            float m2 = ws[6 + a*(11-a)/2 + b] * invN;
            e2 = fmaf(wr[i]*wr[j], m2, e2);
        }
    float var = e2 - mean*mean;
    float a1 = g1[c] * rsqrtf(var + BN_EPS);
    float* wp = ws + 32 + c*8;
    #pragma unroll
    for (int i = 0; i < 6; ++i) wp[i] = a1 * wr[i];
    wp[6] = fmaf(a1, bc - mean, beta1[c]);   // beff
    wp[7] = w2[c];                           // w2c
}

// ---------------- k_main: grid-stride + prefetch, plain-C conv ----------------
__global__ __launch_bounds__(256) void k_main(const float* __restrict__ x,
                                              const float* __restrict__ wts,
                                              const float* __restrict__ zbuf,
                                              const float* __restrict__ b2,
                                              float* __restrict__ stats,
                                              float* __restrict__ opre) {
    __shared__ f4 lw[50];                    // 25 channels x {w0..w3},{w4,w5,beff,w2c}
    int t = threadIdx.x;
    if (t < 50) lw[t] = ((const f4*)wts)[t];
    __syncthreads();

    float b2v = b2[0];
    float l1 = 0.f, l2 = 0.f;
    int T0 = blockIdx.x * NIT_MAIN;

    Rows P = loadrows(x, zbuf, (T0*256 + t) * 4);
    #pragma unroll 1
    for (int it = 0; it < NIT_MAIN; ++it) {
        Rows cur = P;
        if (it + 1 < NIT_MAIN)
            P = loadrows(x, zbuf, ((T0 + it + 1)*256 + t) * 4);

        f4 s[6];
        mkstencil(cur, s);

        f4 o = {b2v, b2v, b2v, b2v};
        #pragma unroll
        for (int c = 0; c < 25; ++c) {
            f4 A = lw[2*c];                  // w0 w1 w2 w3
            f4 B = lw[2*c + 1];              // w4 w5 beff w2c
            f4 tt = {B.z, B.z, B.z, B.z};
            tt += s[0] * A.x;
            tt += s[1] * A.y;
            tt += s[2] * A.z;
            tt += s[3] * A.w;
            tt += s[4] * B.x;
            tt += s[5] * B.y;
            tt = vmax0(tt);
            o += tt * B.w;
        }

        *(f4*)(opre + ((T0 + it)*256 + t) * 4) = o;
        l1 += (o.x + o.y) + (o.z + o.w);
        l2 = fmaf(o.x, o.x, l2); l2 = fmaf(o.y, o.y, l2);
        l2 = fmaf(o.z, o.z, l2); l2 = fmaf(o.w, o.w, l2);
    }

    for (int off = 32; off; off >>= 1) { l1 += __shfl_xor(l1, off); l2 += __shfl_xor(l2, off); }
    __shared__ float red[2][4];
    int wave = t >> 6, lane = t & 63;
    if (lane == 0) { red[0][wave] = l1; red[1][wave] = l2; }
    __syncthreads();
    if (t == 0) atomicAdd(&stats[27], red[0][0]+red[0][1]+red[0][2]+red[0][3]);
    if (t == 1) atomicAdd(&stats[28], red[1][0]+red[1][1]+red[1][2]+red[1][3]);
}

__global__ void k_stats2(const float* g2, const float* beta2, float* ws) {
    const float invN = 1.f / (float)NPIX;
    float mean = ws[27] * invN;
    float var  = ws[28] * invN - mean*mean;
    float a2 = g2[0] * rsqrtf(var + BN_EPS);
    ws[29] = a2;
    ws[30] = fmaf(-mean, a2, beta2[0]);
}

__global__ __launch_bounds__(256) void k_final(const float* __restrict__ x,
                                               const float* ws,
                                               float* out) {
    int idx = blockIdx.x * 256 + threadIdx.x;   // float4 index
    float a2 = ws[29], c2 = ws[30];
    f4 o  = ((const f4*)out)[idx];
    f4 xv = ((const f4*)x)[idx];
    f4 r;
    r.x = fmaxf(fmaf(a2, o.x, c2), 0.f) + xv.x;
    r.y = fmaxf(fmaf(a2, o.y, c2), 0.f) + xv.y;
    r.z = fmaxf(fmaf(a2, o.z, c2), 0.f) + xv.z;
    r.w = fmaxf(fmaf(a2, o.w, c2), 0.f) + xv.w;
    ((f4*)out)[idx] = r;
}

extern "C" void kernel_launch(void* const* d_in, const int* in_sizes, int n_in,
                              void* d_out, int out_size, void* d_ws, size_t ws_size,
                              hipStream_t stream) {
    const float* x     = (const float*)d_in[0];
    const float* w1    = (const float*)d_in[1];
    const float* b1    = (const float*)d_in[2];
    const float* g1    = (const float*)d_in[3];
    const float* beta1 = (const float*)d_in[4];
    const float* w2    = (const float*)d_in[5];
    const float* b2    = (const float*)d_in[6];
    const float* g2    = (const float*)d_in[7];
    const float* beta2 = (const float*)d_in[8];
    float* out = (float*)d_out;
    float* ws  = (float*)d_ws;

    hipMemsetAsync(ws, 0, 2048, stream);
    k_moments<<<GRID_MOM, 256, 0, stream>>>(x, ws);
    k_stats1 <<<1, 32, 0, stream>>>(w1, b1, g1, beta1, w2, ws);
    k_main   <<<GRID_MAIN, 256, 0, stream>>>(x, ws + 32, ws + 400, b2, ws, out);
    k_stats2 <<<1, 1, 0, stream>>>(g2, beta2, ws);
    k_final  <<<8192, 256, 0, stream>>>(x, ws, out);
}

// Round 11
// 140.781 us; speedup vs baseline: 10.7380x; 10.7227x over previous
//
#include <hip/hip_runtime.h>

typedef float f4 __attribute__((ext_vector_type(4)));

#define NPIX (32*512*512)        // 8388608
#define BN_EPS 1e-5f
#define GRID_BIG 2048            // blocks for k_moments / k_main / k_final
// each block: 256 threads x 4 f4-groups = 4096 px; 2048*4096 = NPIX

// ws float layout:
// [0..5]   M1 sums of s_i
// [6..26]  M2 sums (upper tri, idx = 6 + a*(11-a)/2 + b, a<=b)
// [27]     S1 (sum o_pre), [28] S2 (sum o_pre^2)
// [29]     a2, [30] c2
// [32..256)  wpack[28][8] = {a1w0..a1w5, beff, w2c}; ch 25..27 stay zero
// [400..]  zbuf (zero region)
// memset clears first 2048 bytes (floats 0..511) each launch.

struct Rows { f4 C, N, S; float wv, ev, nwv, sev; };

__device__ __forceinline__ Rows loadrows(const float* __restrict__ x,
                                         const float* zbuf, int p) {
    Rows r;
    int rem = p & (512*512 - 1);
    int i = rem >> 9, jj = rem & 511;          // jj multiple of 4
    const float* xc = x + p;
    const float* xn = (i > 0)   ? xc - 512 : zbuf;
    const float* xs = (i < 511) ? xc + 512 : zbuf;
    r.C = *(const f4*)xc;
    r.N = *(const f4*)xn;
    r.S = *(const f4*)xs;
    bool hw = (jj > 0), he = (jj < 508);
    float wv  = xc[hw ? -1 : 0];
    float ev  = xc[he ?  4 : 3];
    float nwv = xn[hw ? -1 : 0];
    float sev = xs[he ?  4 : 3];
    r.wv  = hw ? wv  : 0.f;
    r.ev  = he ? ev  : 0.f;
    r.nwv = hw ? nwv : 0.f;
    r.sev = he ? sev : 0.f;
    return r;
}

__device__ __forceinline__ void mkstencil(const Rows& r, f4* s) {
    f4 E   = {r.C.y, r.C.z, r.C.w, r.ev};
    f4 W   = {r.wv,  r.C.x, r.C.y, r.C.z};
    f4 Ssh = {r.S.y, r.S.z, r.S.w, r.sev};
    f4 Nsh = {r.nwv, r.N.x, r.N.y, r.N.z};
    s[0] = r.C;
    s[1] = (r.S - r.N) * 0.5f;
    s[2] = (E - W) * 0.5f;
    s[3] = r.S + r.N - 2.f*r.C;
    s[4] = E + W - 2.f*r.C;
    s[5] = Ssh + Nsh - r.S - E;
}

__device__ __forceinline__ f4 fma4(f4 a, float b, f4 c) {
    f4 r;
    r.x = fmaf(a.x, b, c.x); r.y = fmaf(a.y, b, c.y);
    r.z = fmaf(a.z, b, c.z); r.w = fmaf(a.w, b, c.w);
    return r;
}

__device__ __forceinline__ f4 fma44(f4 a, f4 b, f4 c) {
    f4 r;
    r.x = fmaf(a.x, b.x, c.x); r.y = fmaf(a.y, b.y, c.y);
    r.z = fmaf(a.z, b.z, c.z); r.w = fmaf(a.w, b.w, c.w);
    return r;
}

__device__ __forceinline__ f4 vmax0(f4 a) {
    f4 r;
    r.x = fmaxf(a.x, 0.f); r.y = fmaxf(a.y, 0.f);
    r.z = fmaxf(a.z, 0.f); r.w = fmaxf(a.w, 0.f);
    return r;
}

// ---------------- k_moments: 16 px/thread, f4 accumulators ----------------
__global__ __launch_bounds__(256) void k_moments(const float* __restrict__ x,
                                                 float* ws) {
    const float* zbuf = ws + 400;
    int t = threadIdx.x;
    int g0 = blockIdx.x * 1024 + t;            // first f4-group of this thread
    f4 acc[27];
    #pragma unroll
    for (int i = 0; i < 27; ++i) acc[i] = (f4){0.f, 0.f, 0.f, 0.f};

    #pragma unroll
    for (int q = 0; q < 4; ++q) {
        Rows r = loadrows(x, zbuf, (g0 + 256*q) * 4);
        f4 s[6];
        mkstencil(r, s);
        #pragma unroll
        for (int a = 0; a < 6; ++a) {
            acc[a] += s[a];
            #pragma unroll
            for (int b = a; b < 6; ++b) {
                int idx = 6 + a*(11-a)/2 + b;
                acc[idx] = fma44(s[a], s[b], acc[idx]);
            }
        }
    }
    // horizontal fold + wave reduce
    __shared__ float red[27][4];
    int wave = t >> 6, lane = t & 63;
    #pragma unroll
    for (int i = 0; i < 27; ++i) {
        float v = (acc[i].x + acc[i].y) + (acc[i].z + acc[i].w);
        for (int off = 32; off; off >>= 1) v += __shfl_xor(v, off);
        if (lane == 0) red[i][wave] = v;
    }
    __syncthreads();
    if (t < 27) atomicAdd(&ws[t], red[t][0] + red[t][1] + red[t][2] + red[t][3]);
}

__global__ void k_stats1(const float* w1, const float* b1, const float* g1,
                         const float* beta1, const float* w2, float* ws) {
    int c = threadIdx.x;
    if (c >= 25) return;
    const float invN = 1.f / (float)NPIX;
    float m1[6], wr[6];
    #pragma unroll
    for (int i = 0; i < 6; ++i) m1[i] = ws[i] * invN;
    #pragma unroll
    for (int i = 0; i < 6; ++i) wr[i] = w1[c*6 + i];
    float bc = b1[c];
    float mean = bc;
    #pragma unroll
    for (int i = 0; i < 6; ++i) mean = fmaf(wr[i], m1[i], mean);
    float e2 = bc * bc;
    #pragma unroll
    for (int i = 0; i < 6; ++i) e2 = fmaf(2.f*bc*wr[i], m1[i], e2);
    #pragma unroll
    for (int i = 0; i < 6; ++i)
        #pragma unroll
        for (int j = 0; j < 6; ++j) {
            int a = i < j ? i : j, b = i < j ? j : i;
            float m2 = ws[6 + a*(11-a)/2 + b] * invN;
            e2 = fmaf(wr[i]*wr[j], m2, e2);
        }
    float var = e2 - mean*mean;
    float a1 = g1[c] * rsqrtf(var + BN_EPS);
    float* wp = ws + 32 + c*8;
    #pragma unroll
    for (int i = 0; i < 6; ++i) wp[i] = a1 * wr[i];
    wp[6] = fmaf(a1, bc - mean, beta1[c]);   // beff
    wp[7] = w2[c];                           // w2c
}

// ---------------- k_main: 16 px/thread, weights via SGPR groups ----------------
__global__ __launch_bounds__(256) void k_main(const float* __restrict__ x,
                                              const float* __restrict__ wts,
                                              const float* __restrict__ zbuf,
                                              const float* __restrict__ b2,
                                              float* __restrict__ stats,
                                              float* __restrict__ opre) {
    int t = threadIdx.x;
    int g0 = blockIdx.x * 1024 + t;            // first f4-group of this thread

    // build all 4 stencils up front (s[4][6] stays in VGPRs)
    f4 s[4][6];
    #pragma unroll
    for (int q = 0; q < 4; ++q) {
        Rows r = loadrows(x, zbuf, (g0 + 256*q) * 4);
        mkstencil(r, s[q]);
    }

    float b2v = b2[0];
    f4 o[4];
    #pragma unroll
    for (int q = 0; q < 4; ++q) o[q] = (f4){b2v, b2v, b2v, b2v};

    // 4 channel-groups of 7; wts is a uniform kernel-arg pointer -> s_load.
    // '#pragma unroll 1' keeps only one group's 56 floats live in SGPRs.
    #pragma unroll 1
    for (int g = 0; g < 4; ++g) {
        const float* wp = wts + g * 56;
        #pragma unroll
        for (int c = 0; c < 7; ++c) {
            const float* wc = wp + c * 8;
            float W0 = wc[0], W1 = wc[1], W2 = wc[2], W3 = wc[3];
            float W4 = wc[4], W5 = wc[5], BE = wc[6], WO = wc[7];
            #pragma unroll
            for (int q = 0; q < 4; ++q) {
                f4 tt = {BE, BE, BE, BE};
                tt = fma4(s[q][0], W0, tt);
                tt = fma4(s[q][1], W1, tt);
                tt = fma4(s[q][2], W2, tt);
                tt = fma4(s[q][3], W3, tt);
                tt = fma4(s[q][4], W4, tt);
                tt = fma4(s[q][5], W5, tt);
                tt = vmax0(tt);
                o[q] = fma4(tt, WO, o[q]);
            }
        }
    }

    float l1 = 0.f, l2 = 0.f;
    #pragma unroll
    for (int q = 0; q < 4; ++q) {
        *(f4*)(opre + (g0 + 256*q) * 4) = o[q];
        l1 += (o[q].x + o[q].y) + (o[q].z + o[q].w);
        l2 = fmaf(o[q].x, o[q].x, l2); l2 = fmaf(o[q].y, o[q].y, l2);
        l2 = fmaf(o[q].z, o[q].z, l2); l2 = fmaf(o[q].w, o[q].w, l2);
    }
    for (int off = 32; off; off >>= 1) { l1 += __shfl_xor(l1, off); l2 += __shfl_xor(l2, off); }
    __shared__ float red[2][4];
    int wave = t >> 6, lane = t & 63;
    if (lane == 0) { red[0][wave] = l1; red[1][wave] = l2; }
    __syncthreads();
    if (t == 0) atomicAdd(&stats[27], red[0][0]+red[0][1]+red[0][2]+red[0][3]);
    if (t == 1) atomicAdd(&stats[28], red[1][0]+red[1][1]+red[1][2]+red[1][3]);
}

__global__ void k_stats2(const float* g2, const float* beta2, float* ws) {
    const float invN = 1.f / (float)NPIX;
    float mean = ws[27] * invN;
    float var  = ws[28] * invN - mean*mean;
    float a2 = g2[0] * rsqrtf(var + BN_EPS);
    ws[29] = a2;
    ws[30] = fmaf(-mean, a2, beta2[0]);
}

__global__ __launch_bounds__(256) void k_final(const float* __restrict__ x,
                                               const float* __restrict__ ws,
                                               float* __restrict__ out) {
    int t = threadIdx.x;
    float a2 = ws[29], c2 = ws[30];
    int base = blockIdx.x * 1024 + t;          // f4 index
    #pragma unroll
    for (int it = 0; it < 4; ++it) {
        int idx = base + it * 256;
        f4 o  = ((const f4*)out)[idx];
        f4 xv = ((const f4*)x)[idx];
        f4 r;
        r.x = fmaxf(fmaf(a2, o.x, c2), 0.f) + xv.x;
        r.y = fmaxf(fmaf(a2, o.y, c2), 0.f) + xv.y;
        r.z = fmaxf(fmaf(a2, o.z, c2), 0.f) + xv.z;
        r.w = fmaxf(fmaf(a2, o.w, c2), 0.f) + xv.w;
        ((f4*)out)[idx] = r;
    }
}

extern "C" void kernel_launch(void* const* d_in, const int* in_sizes, int n_in,
                              void* d_out, int out_size, void* d_ws, size_t ws_size,
                              hipStream_t stream) {
    const float* x     = (const float*)d_in[0];
    const float* w1    = (const float*)d_in[1];
    const float* b1    = (const float*)d_in[2];
    const float* g1    = (const float*)d_in[3];
    const float* beta1 = (const float*)d_in[4];
    const float* w2    = (const float*)d_in[5];
    const float* b2    = (const float*)d_in[6];
    const float* g2    = (const float*)d_in[7];
    const float* beta2 = (const float*)d_in[8];
    float* out = (float*)d_out;
    float* ws  = (float*)d_ws;

    hipMemsetAsync(ws, 0, 2048, stream);
    k_moments<<<GRID_BIG, 256, 0, stream>>>(x, ws);
    k_stats1 <<<1, 32, 0, stream>>>(w1, b1, g1, beta1, w2, ws);
    k_main   <<<GRID_BIG, 256, 0, stream>>>(x, ws + 32, ws + 400, b2, ws, out);
    k_stats2 <<<1, 1, 0, stream>>>(g2, beta2, ws);
    k_final  <<<GRID_BIG, 256, 0, stream>>>(x, ws, out);
}